// Round 7
// baseline (372.949 us; speedup 1.0000x reference)
//
#include <hip/hip_runtime.h>

// bf16 helpers (manual, round-to-nearest-even)
__device__ __forceinline__ unsigned short f2bf(float f) {
  unsigned int u = __float_as_uint(f);
  unsigned int r = (u + 0x7FFFu + ((u >> 16) & 1u)) >> 16;
  return (unsigned short)r;
}
__device__ __forceinline__ float bf_lo(unsigned int u) { return __uint_as_float(u << 16); }
__device__ __forceinline__ float bf_hi(unsigned int u) { return __uint_as_float(u & 0xFFFF0000u); }

// ---------------- degree / CSR build ----------------

__global__ void k_init_deg(int* __restrict__ deg, int n) {
  int i = blockIdx.x * blockDim.x + threadIdx.x;
  if (i < n) deg[i] = 1;  // self-loop
}

__global__ void k_count(const int* __restrict__ dst, int* __restrict__ deg, int e) {
  int i = blockIdx.x * blockDim.x + threadIdx.x;
  if (i < e) atomicAdd(&deg[dst[i]], 1);
}

__global__ void k_dinv(const int* __restrict__ deg, float* __restrict__ dinv, int n) {
  int i = blockIdx.x * blockDim.x + threadIdx.x;
  if (i < n) dinv[i] = rsqrtf((float)deg[i]);
}

__global__ void k_scan1(const int* __restrict__ deg, int* __restrict__ rp,
                        int* __restrict__ psum, int n) {
  __shared__ int s[256];
  int tid = threadIdx.x;
  int i = blockIdx.x * 256 + tid;
  int v = (i < n) ? deg[i] : 0;
  int x = v;
  s[tid] = x; __syncthreads();
  for (int off = 1; off < 256; off <<= 1) {
    int t = (tid >= off) ? s[tid - off] : 0;
    __syncthreads();
    x += t; s[tid] = x;
    __syncthreads();
  }
  if (i < n) rp[i] = x - v;                 // exclusive within block
  if (tid == 255) psum[blockIdx.x] = x;     // block total
}

__global__ void k_scan2(int* __restrict__ psum, int nb) {
  __shared__ int s[256];
  int tid = threadIdx.x;
  int v = (tid < nb) ? psum[tid] : 0;
  int x = v;
  s[tid] = x; __syncthreads();
  for (int off = 1; off < 256; off <<= 1) {
    int t = (tid >= off) ? s[tid - off] : 0;
    __syncthreads();
    x += t; s[tid] = x;
    __syncthreads();
  }
  if (tid < nb) psum[tid] = x - v;          // exclusive prefix of block sums
}

__global__ void k_scan3(int* __restrict__ rp, int* __restrict__ cursor,
                        const int* __restrict__ psum, int n, int total) {
  int i = blockIdx.x * blockDim.x + threadIdx.x;
  if (i < n) {
    int r = rp[i] + psum[i >> 8];
    rp[i] = r;
    cursor[i] = r;
  }
  if (i == 0) rp[n] = total;
}

__global__ void k_scatter(const int* __restrict__ src, const int* __restrict__ dst,
                          const float* __restrict__ dinv, int* __restrict__ cursor,
                          int2* __restrict__ csr, int e, int n) {
  int i = blockIdx.x * blockDim.x + threadIdx.x;
  if (i >= e + n) return;
  int s, d;
  if (i < e) { s = src[i]; d = dst[i]; }
  else       { s = d = i - e; }             // self-loop
  int pos = atomicAdd(&cursor[d], 1);
  float w = dinv[s] * dinv[d];
  csr[pos] = make_int2(s, __float_as_int(w));
}

// fp32 -> bf16 array convert (for L1-resident weight reads)
__global__ void k_f2bf(const float* __restrict__ in, unsigned short* __restrict__ out, int n) {
  int i = blockIdx.x * blockDim.x + threadIdx.x;
  if (i < n) out[i] = f2bf(in[i]);
}

// ---------------- aggregation (pull, CSR by dst) ----------------

// width-7 aggregation on raw x: lane per edge + butterfly reduce
__global__ void k_agg7(const float* __restrict__ x, const int2* __restrict__ csr,
                       const int* __restrict__ rp, float* __restrict__ out, int n) {
  int gid = blockIdx.x * blockDim.x + threadIdx.x;
  int v = gid >> 6, lane = gid & 63;
  if (v >= n) return;
  int beg = rp[v], end = rp[v + 1];
  float a[7] = {0.f, 0.f, 0.f, 0.f, 0.f, 0.f, 0.f};
  for (int base = beg; base < end; base += 64) {
    int cnt = end - base; if (cnt > 64) cnt = 64;
    if (lane < cnt) {
      int2 e = csr[base + lane];
      float w = __int_as_float(e.y);
      const float* xr = x + (size_t)e.x * 7;
#pragma unroll
      for (int f = 0; f < 7; ++f) a[f] += w * xr[f];
    }
  }
#pragma unroll
  for (int off = 32; off > 0; off >>= 1) {
#pragma unroll
    for (int f = 0; f < 7; ++f) a[f] += __shfl_xor(a[f], off);
  }
  if (lane == 0) {
#pragma unroll
    for (int f = 0; f < 7; ++f) out[(size_t)v * 7 + f] = a[f];
  }
}

// width-128 bf16 aggregation: 32 lanes per node (2 nodes/wave), uint2 (4 bf16)
// per lane -> 256B row. fp32 accumulate, fp32 out.
__global__ void k_agg128(const unsigned short* __restrict__ t, const int2* __restrict__ csr,
                         const int* __restrict__ rp, float* __restrict__ out, int n) {
  int gid = blockIdx.x * blockDim.x + threadIdx.x;
  int v = gid >> 5, lane = gid & 31;
  if (v >= n) return;
  int beg = rp[v], end = rp[v + 1];
  float4 a = make_float4(0.f, 0.f, 0.f, 0.f);
  const uint2* tp = (const uint2*)t + lane;   // row stride = 32 uint2 (128 bf16)
  for (int base = beg; base < end; base += 32) {
    int cnt = end - base; if (cnt > 32) cnt = 32;
    int2 e = csr[base + (lane < cnt ? lane : cnt - 1)];
    int j = 0;
    for (; j + 4 <= cnt; j += 4) {
      int s0 = __shfl(e.x, j + 0, 32), s1 = __shfl(e.x, j + 1, 32);
      int s2 = __shfl(e.x, j + 2, 32), s3 = __shfl(e.x, j + 3, 32);
      float w0 = __int_as_float(__shfl(e.y, j + 0, 32));
      float w1 = __int_as_float(__shfl(e.y, j + 1, 32));
      float w2 = __int_as_float(__shfl(e.y, j + 2, 32));
      float w3 = __int_as_float(__shfl(e.y, j + 3, 32));
      uint2 r0 = tp[(size_t)s0 * 32];
      uint2 r1 = tp[(size_t)s1 * 32];
      uint2 r2 = tp[(size_t)s2 * 32];
      uint2 r3 = tp[(size_t)s3 * 32];
      a.x += w0 * bf_lo(r0.x); a.y += w0 * bf_hi(r0.x); a.z += w0 * bf_lo(r0.y); a.w += w0 * bf_hi(r0.y);
      a.x += w1 * bf_lo(r1.x); a.y += w1 * bf_hi(r1.x); a.z += w1 * bf_lo(r1.y); a.w += w1 * bf_hi(r1.y);
      a.x += w2 * bf_lo(r2.x); a.y += w2 * bf_hi(r2.x); a.z += w2 * bf_lo(r2.y); a.w += w2 * bf_hi(r2.y);
      a.x += w3 * bf_lo(r3.x); a.y += w3 * bf_hi(r3.x); a.z += w3 * bf_lo(r3.y); a.w += w3 * bf_hi(r3.y);
    }
    for (; j < cnt; ++j) {
      int s0 = __shfl(e.x, j, 32);
      float w0 = __int_as_float(__shfl(e.y, j, 32));
      uint2 r0 = tp[(size_t)s0 * 32];
      a.x += w0 * bf_lo(r0.x); a.y += w0 * bf_hi(r0.x); a.z += w0 * bf_lo(r0.y); a.w += w0 * bf_hi(r0.y);
    }
  }
  ((float4*)(out + (size_t)v * 128))[lane] = a;
}

// width-64 bf16 aggregation + bias: 16 lanes per node (4 nodes/wave), uint2 per
// lane -> 128B row = ONE cache line per edge. fp32 accumulate, fp32 out.
__global__ void k_agg64b(const unsigned short* __restrict__ t, const int2* __restrict__ csr,
                         const int* __restrict__ rp, const float* __restrict__ bias,
                         float* __restrict__ out, int n) {
  int gid = blockIdx.x * blockDim.x + threadIdx.x;
  int v = gid >> 4, lane = gid & 15;
  if (v >= n) return;
  int beg = rp[v], end = rp[v + 1];
  float4 a = make_float4(0.f, 0.f, 0.f, 0.f);
  const uint2* tp = (const uint2*)t + lane;   // row stride = 16 uint2 (64 bf16)
  for (int base = beg; base < end; base += 16) {
    int cnt = end - base; if (cnt > 16) cnt = 16;
    int2 e = csr[base + (lane < cnt ? lane : cnt - 1)];
    int j = 0;
    for (; j + 4 <= cnt; j += 4) {
      int s0 = __shfl(e.x, j + 0, 16), s1 = __shfl(e.x, j + 1, 16);
      int s2 = __shfl(e.x, j + 2, 16), s3 = __shfl(e.x, j + 3, 16);
      float w0 = __int_as_float(__shfl(e.y, j + 0, 16));
      float w1 = __int_as_float(__shfl(e.y, j + 1, 16));
      float w2 = __int_as_float(__shfl(e.y, j + 2, 16));
      float w3 = __int_as_float(__shfl(e.y, j + 3, 16));
      uint2 r0 = tp[(size_t)s0 * 16];
      uint2 r1 = tp[(size_t)s1 * 16];
      uint2 r2 = tp[(size_t)s2 * 16];
      uint2 r3 = tp[(size_t)s3 * 16];
      a.x += w0 * bf_lo(r0.x); a.y += w0 * bf_hi(r0.x); a.z += w0 * bf_lo(r0.y); a.w += w0 * bf_hi(r0.y);
      a.x += w1 * bf_lo(r1.x); a.y += w1 * bf_hi(r1.x); a.z += w1 * bf_lo(r1.y); a.w += w1 * bf_hi(r1.y);
      a.x += w2 * bf_lo(r2.x); a.y += w2 * bf_hi(r2.x); a.z += w2 * bf_lo(r2.y); a.w += w2 * bf_hi(r2.y);
      a.x += w3 * bf_lo(r3.x); a.y += w3 * bf_hi(r3.x); a.z += w3 * bf_lo(r3.y); a.w += w3 * bf_hi(r3.y);
    }
    for (; j < cnt; ++j) {
      int s0 = __shfl(e.x, j, 16);
      float w0 = __int_as_float(__shfl(e.y, j, 16));
      uint2 r0 = tp[(size_t)s0 * 16];
      a.x += w0 * bf_lo(r0.x); a.y += w0 * bf_hi(r0.x); a.z += w0 * bf_lo(r0.y); a.w += w0 * bf_hi(r0.y);
    }
  }
  const float4 b4 = ((const float4*)bias)[lane];
  a.x += b4.x; a.y += b4.y; a.z += b4.z; a.w += b4.w;
  ((float4*)(out + (size_t)v * 64))[lane] = a;
}

// ---------------- GEMMs (fp32 FMA, bf16 weights from L1) ----------------

// [n,7] @ [7,128] + b, relu -> bf16 out. block = 2 rows x 128 cols
__global__ __launch_bounds__(256) void k_gemm1(const float* __restrict__ A,
                                               const float* __restrict__ W,
                                               const float* __restrict__ bias,
                                               unsigned short* __restrict__ out, int n) {
  __shared__ float ws[7 * 128];
  for (int j = threadIdx.x; j < 7 * 128; j += 256) ws[j] = W[j];
  __syncthreads();
  int r = blockIdx.x * 2 + (threadIdx.x >> 7);
  int c = threadIdx.x & 127;
  if (r >= n) return;
  const float* a = A + (size_t)r * 7;
  float acc = bias[c];
#pragma unroll
  for (int k = 0; k < 7; ++k) acc += a[k] * ws[k * 128 + c];
  out[(size_t)r * 128 + c] = f2bf(fmaxf(acc, 0.f));
}

// [n,128] @ [128,128] + b, relu. No LDS, no barriers: W pre-converted to bf16
// (32KB -> L1-resident), each lane streams its column pair straight from global.
// wave = 8 rows, lane = cols (2l, 2l+1).
__global__ __launch_bounds__(256) void k_gemm2(const float* __restrict__ H,
                                               const unsigned int* __restrict__ Wb,
                                               const float* __restrict__ bias,
                                               float* __restrict__ out, int n) {
  int wave = threadIdx.x >> 6, lane = threadIdx.x & 63;
  int r0 = blockIdx.x * 32 + wave * 8;
  if (r0 >= n) return;
  int rr[8];
#pragma unroll
  for (int i = 0; i < 8; ++i) rr[i] = min(r0 + i, n - 1);
  float acc[8][2] = {};
  const unsigned int* wp = Wb + lane;   // [k][64] uints; lane = col pair
  for (int k = 0; k < 128; k += 4) {
    float h[8][4];
#pragma unroll
    for (int i = 0; i < 8; ++i) {
      float4 t4 = *(const float4*)(H + (size_t)rr[i] * 128 + k);
      h[i][0] = t4.x; h[i][1] = t4.y; h[i][2] = t4.z; h[i][3] = t4.w;
    }
    unsigned int wv[4];
#pragma unroll
    for (int kk = 0; kk < 4; ++kk) wv[kk] = wp[(k + kk) * 64];
#pragma unroll
    for (int kk = 0; kk < 4; ++kk) {
      float w0 = bf_lo(wv[kk]), w1 = bf_hi(wv[kk]);
#pragma unroll
      for (int i = 0; i < 8; ++i) {
        acc[i][0] += h[i][kk] * w0;
        acc[i][1] += h[i][kk] * w1;
      }
    }
  }
  float2 b2 = *(const float2*)&bias[2 * lane];
#pragma unroll
  for (int i = 0; i < 8; ++i) {
    if (r0 + i < n) {
      float2 o = make_float2(fmaxf(acc[i][0] + b2.x, 0.f),
                             fmaxf(acc[i][1] + b2.y, 0.f));
      *(float2*)(out + (size_t)(r0 + i) * 128 + 2 * lane) = o;
    }
  }
}

// [n,128] @ [128,64] -> bf16 out. No LDS/barriers: W3 bf16 (16KB, L1-resident).
// wave = 8 rows, lane = 1 col.
__global__ __launch_bounds__(256) void k_gemm3(const float* __restrict__ H,
                                               const unsigned short* __restrict__ Wb,
                                               unsigned short* __restrict__ out, int n) {
  int wave = threadIdx.x >> 6, lane = threadIdx.x & 63;
  int r0 = blockIdx.x * 32 + wave * 8;
  if (r0 >= n) return;
  int rr[8];
#pragma unroll
  for (int i = 0; i < 8; ++i) rr[i] = min(r0 + i, n - 1);
  float acc[8] = {};
  const unsigned short* wp = Wb + lane;   // [k][64]
  for (int k = 0; k < 128; k += 4) {
    float h[8][4];
#pragma unroll
    for (int i = 0; i < 8; ++i) {
      float4 t4 = *(const float4*)(H + (size_t)rr[i] * 128 + k);
      h[i][0] = t4.x; h[i][1] = t4.y; h[i][2] = t4.z; h[i][3] = t4.w;
    }
    float w[4];
#pragma unroll
    for (int kk = 0; kk < 4; ++kk)
      w[kk] = __uint_as_float(((unsigned int)wp[(k + kk) * 64]) << 16);
#pragma unroll
    for (int kk = 0; kk < 4; ++kk) {
#pragma unroll
      for (int i = 0; i < 8; ++i) acc[i] += h[i][kk] * w[kk];
    }
  }
#pragma unroll
  for (int i = 0; i < 8; ++i)
    if (r0 + i < n) out[(size_t)(r0 + i) * 64 + lane] = f2bf(acc[i]);
}

// ---------------- mean pool over sorted batch (node-parallel) ----------------

__global__ void k_zero(float* __restrict__ p, int n) {
  int i = blockIdx.x * blockDim.x + threadIdx.x;
  if (i < n) p[i] = 0.f;
}

__global__ void k_pool1(const float* __restrict__ h, const int* __restrict__ batch,
                        float* __restrict__ sums, int n) {
  int gid = blockIdx.x * blockDim.x + threadIdx.x;
  int w = gid >> 6, f = gid & 63;
  int i0 = w * 16;
  if (i0 >= n) return;
  int i1 = min(i0 + 16, n);
  int cur = batch[i0];
  float acc = 0.f;
  for (int i = i0; i < i1; ++i) {
    int g = batch[i];
    if (g != cur) {
      atomicAdd(&sums[cur * 64 + f], acc);
      acc = 0.f; cur = g;
    }
    acc += h[(size_t)i * 64 + f];
  }
  atomicAdd(&sums[cur * 64 + f], acc);
}

__global__ void k_pool2(const float* __restrict__ sums, const int* __restrict__ batch,
                        float* __restrict__ pooled, int n) {
  int g = blockIdx.x, f = threadIdx.x;
  int lo = 0, hi = n;
  while (lo < hi) { int m = (lo + hi) >> 1; if (batch[m] < g) lo = m + 1; else hi = m; }
  int start = lo;
  hi = n;
  while (lo < hi) { int m = (lo + hi) >> 1; if (batch[m] < g + 1) lo = m + 1; else hi = m; }
  float cnt = (float)(lo - start);
  pooled[g * 64 + f] = sums[g * 64 + f] / fmaxf(cnt, 1.f);
}

// ---------------- launch ----------------

extern "C" void kernel_launch(void* const* d_in, const int* in_sizes, int n_in,
                              void* d_out, int out_size, void* d_ws, size_t ws_size,
                              hipStream_t stream) {
  const float* x   = (const float*)d_in[0];
  const int* eidx  = (const int*)d_in[1];
  const int* batch = (const int*)d_in[2];
  const float* W1  = (const float*)d_in[3];
  const float* b1  = (const float*)d_in[4];
  const float* W2  = (const float*)d_in[5];
  const float* b2  = (const float*)d_in[6];
  const float* W3  = (const float*)d_in[7];
  const float* b3  = (const float*)d_in[8];
  float* out = (float*)d_out;

  const int n = in_sizes[0] / 7;       // 50000
  const int e = in_sizes[1] / 2;       // 800000
  const int G = out_size / 64 - n;     // 50
  const int m = e + n;                 // CSR entries incl self-loops

  // workspace carve-up (4B elements)
  float* wsf = (float*)d_ws;
  int*   wsi = (int*)d_ws;
  size_t off = 0;
  int*   deg    = wsi + off; off += n;
  float* dinv   = wsf + off; off += n;
  int*   rp     = wsi + off; off += (size_t)((n + 1 + 3) & ~3);
  int*   cursor = wsi + off; off += n;
  int*   psum   = wsi + off; off += 256;
  float* sums   = wsf + off; off += (size_t)G * 64;
  unsigned short* wb2 = (unsigned short*)(wsf + off); off += 128 * 128 / 2;  // bf16 W2
  unsigned short* wb3 = (unsigned short*)(wsf + off); off += 128 * 64 / 2;   // bf16 W3
  int2*  csr    = (int2*)(wsi + off); off += (size_t)2 * m;
  float* bufA   = wsf + off; off += (size_t)n * 128;
  float* bufB   = wsf + off; off += (size_t)n * 128;

  // bf16 gather tensors alias the fp32 buffers (dataflow strictly serialized):
  unsigned short* t2 = (unsigned short*)bufB;
  unsigned short* t3 = (unsigned short*)bufA;

  const int* src = eidx;       // edge_index[0]
  const int* dst = eidx + e;   // edge_index[1]

  const int nb = (n + 255) / 256;

  // CSR build
  k_init_deg<<<nb, 256, 0, stream>>>(deg, n);
  k_count<<<(e + 255) / 256, 256, 0, stream>>>(dst, deg, e);
  k_dinv<<<nb, 256, 0, stream>>>(deg, dinv, n);
  k_scan1<<<nb, 256, 0, stream>>>(deg, rp, psum, n);
  k_scan2<<<1, 256, 0, stream>>>(psum, nb);
  k_scan3<<<nb, 256, 0, stream>>>(rp, cursor, psum, n, m);
  k_scatter<<<(m + 255) / 256, 256, 0, stream>>>(src, dst, dinv, cursor, csr, e, n);
  // zero pooled sums + convert weights to bf16
  k_zero<<<(G * 64 + 255) / 256, 256, 0, stream>>>(sums, G * 64);
  k_f2bf<<<(128 * 128 + 255) / 256, 256, 0, stream>>>(W2, wb2, 128 * 128);
  k_f2bf<<<(128 * 64 + 255) / 256, 256, 0, stream>>>(W3, wb3, 128 * 64);

  // layer 1: AGG(x) [n,7] then @W1 + b1, relu -> bf16 t2
  k_agg7<<<((size_t)n * 64 + 255) / 256, 256, 0, stream>>>(x, csr, rp, bufA, n);
  k_gemm1<<<(n + 1) / 2, 256, 0, stream>>>(bufA, W1, b1, t2, n);

  // layer 2: AGG(t2 bf16) -> bufA fp32, then @W2(bf16) + b2, relu -> bufB fp32
  k_agg128<<<((size_t)n * 32 + 255) / 256, 256, 0, stream>>>(t2, csr, rp, bufA, n);
  k_gemm2<<<(n + 31) / 32, 256, 0, stream>>>(bufA, (const unsigned int*)wb2, b2, bufB, n);

  // layer 3: h2 @ W3(bf16) -> bf16 t3, then AGG + b3 -> d_out
  k_gemm3<<<(n + 31) / 32, 256, 0, stream>>>(bufB, wb3, t3, n);
  k_agg64b<<<((size_t)n * 16 + 255) / 256, 256, 0, stream>>>(t3, csr, rp, b3, out, n);

  // mean pool -> d_out tail (node-parallel + finalize)
  const int waves = (n + 15) / 16;
  k_pool1<<<(waves * 64 + 255) / 256, 256, 0, stream>>>(out, batch, sums, n);
  k_pool2<<<G, 64, 0, stream>>>(sums, batch, out + (size_t)n * 64, n);
}

// Round 8
// 266.607 us; speedup vs baseline: 1.3989x; 1.3989x over previous
//
#include <hip/hip_runtime.h>

typedef short s16x8 __attribute__((ext_vector_type(8)));
typedef float f32x4 __attribute__((ext_vector_type(4)));

// bf16 helpers (manual, round-to-nearest-even)
__device__ __forceinline__ unsigned short f2bf(float f) {
  unsigned int u = __float_as_uint(f);
  unsigned int r = (u + 0x7FFFu + ((u >> 16) & 1u)) >> 16;
  return (unsigned short)r;
}
__device__ __forceinline__ float bf_lo(unsigned int u) { return __uint_as_float(u << 16); }
__device__ __forceinline__ float bf_hi(unsigned int u) { return __uint_as_float(u & 0xFFFF0000u); }

// ---------------- degree / CSR build ----------------

__global__ void k_init_deg(int* __restrict__ deg, int n) {
  int i = blockIdx.x * blockDim.x + threadIdx.x;
  if (i < n) deg[i] = 1;  // self-loop
}

__global__ void k_count(const int* __restrict__ dst, int* __restrict__ deg, int e) {
  int i = blockIdx.x * blockDim.x + threadIdx.x;
  if (i < e) atomicAdd(&deg[dst[i]], 1);
}

__global__ void k_dinv(const int* __restrict__ deg, float* __restrict__ dinv, int n) {
  int i = blockIdx.x * blockDim.x + threadIdx.x;
  if (i < n) dinv[i] = rsqrtf((float)deg[i]);
}

__global__ void k_scan1(const int* __restrict__ deg, int* __restrict__ rp,
                        int* __restrict__ psum, int n) {
  __shared__ int s[256];
  int tid = threadIdx.x;
  int i = blockIdx.x * 256 + tid;
  int v = (i < n) ? deg[i] : 0;
  int x = v;
  s[tid] = x; __syncthreads();
  for (int off = 1; off < 256; off <<= 1) {
    int t = (tid >= off) ? s[tid - off] : 0;
    __syncthreads();
    x += t; s[tid] = x;
    __syncthreads();
  }
  if (i < n) rp[i] = x - v;                 // exclusive within block
  if (tid == 255) psum[blockIdx.x] = x;     // block total
}

__global__ void k_scan2(int* __restrict__ psum, int nb) {
  __shared__ int s[256];
  int tid = threadIdx.x;
  int v = (tid < nb) ? psum[tid] : 0;
  int x = v;
  s[tid] = x; __syncthreads();
  for (int off = 1; off < 256; off <<= 1) {
    int t = (tid >= off) ? s[tid - off] : 0;
    __syncthreads();
    x += t; s[tid] = x;
    __syncthreads();
  }
  if (tid < nb) psum[tid] = x - v;          // exclusive prefix of block sums
}

__global__ void k_scan3(int* __restrict__ rp, int* __restrict__ cursor,
                        const int* __restrict__ psum, int n, int total) {
  int i = blockIdx.x * blockDim.x + threadIdx.x;
  if (i < n) {
    int r = rp[i] + psum[i >> 8];
    rp[i] = r;
    cursor[i] = r;
  }
  if (i == 0) rp[n] = total;
}

__global__ void k_scatter(const int* __restrict__ src, const int* __restrict__ dst,
                          const float* __restrict__ dinv, int* __restrict__ cursor,
                          int2* __restrict__ csr, int e, int n) {
  int i = blockIdx.x * blockDim.x + threadIdx.x;
  if (i >= e + n) return;
  int s, d;
  if (i < e) { s = src[i]; d = dst[i]; }
  else       { s = d = i - e; }             // self-loop
  int pos = atomicAdd(&cursor[d], 1);
  float w = dinv[s] * dinv[d];
  csr[pos] = make_int2(s, __float_as_int(w));
}

// W [K x N] fp32 -> Wt [N x K] bf16 (transposed, for contiguous B-fragment loads)
__global__ void k_wtr(const float* __restrict__ W, unsigned short* __restrict__ Wt,
                      int K, int N) {
  int i = blockIdx.x * blockDim.x + threadIdx.x;
  if (i < K * N) {
    int k = i / N, c = i - k * N;
    Wt[(size_t)c * K + k] = f2bf(W[i]);
  }
}

// ---------------- aggregation (pull, CSR by dst) ----------------

// width-7 aggregation on raw x: lane per edge + butterfly reduce
__global__ void k_agg7(const float* __restrict__ x, const int2* __restrict__ csr,
                       const int* __restrict__ rp, float* __restrict__ out, int n) {
  int gid = blockIdx.x * blockDim.x + threadIdx.x;
  int v = gid >> 6, lane = gid & 63;
  if (v >= n) return;
  int beg = rp[v], end = rp[v + 1];
  float a[7] = {0.f, 0.f, 0.f, 0.f, 0.f, 0.f, 0.f};
  for (int base = beg; base < end; base += 64) {
    int cnt = end - base; if (cnt > 64) cnt = 64;
    if (lane < cnt) {
      int2 e = csr[base + lane];
      float w = __int_as_float(e.y);
      const float* xr = x + (size_t)e.x * 7;
#pragma unroll
      for (int f = 0; f < 7; ++f) a[f] += w * xr[f];
    }
  }
#pragma unroll
  for (int off = 32; off > 0; off >>= 1) {
#pragma unroll
    for (int f = 0; f < 7; ++f) a[f] += __shfl_xor(a[f], off);
  }
  if (lane == 0) {
#pragma unroll
    for (int f = 0; f < 7; ++f) out[(size_t)v * 7 + f] = a[f];
  }
}

// width-128 bf16 aggregation: 32 lanes/node, uint2 (4 bf16)/lane.
// fp32 accumulate, bf16 out (feeds MFMA gemm2).
__global__ void k_agg128(const unsigned short* __restrict__ t, const int2* __restrict__ csr,
                         const int* __restrict__ rp, unsigned short* __restrict__ out, int n) {
  int gid = blockIdx.x * blockDim.x + threadIdx.x;
  int v = gid >> 5, lane = gid & 31;
  if (v >= n) return;
  int beg = rp[v], end = rp[v + 1];
  float4 a = make_float4(0.f, 0.f, 0.f, 0.f);
  const uint2* tp = (const uint2*)t + lane;   // row stride = 32 uint2 (128 bf16)
  for (int base = beg; base < end; base += 32) {
    int cnt = end - base; if (cnt > 32) cnt = 32;
    int2 e = csr[base + (lane < cnt ? lane : cnt - 1)];
    int j = 0;
    for (; j + 4 <= cnt; j += 4) {
      int s0 = __shfl(e.x, j + 0, 32), s1 = __shfl(e.x, j + 1, 32);
      int s2 = __shfl(e.x, j + 2, 32), s3 = __shfl(e.x, j + 3, 32);
      float w0 = __int_as_float(__shfl(e.y, j + 0, 32));
      float w1 = __int_as_float(__shfl(e.y, j + 1, 32));
      float w2 = __int_as_float(__shfl(e.y, j + 2, 32));
      float w3 = __int_as_float(__shfl(e.y, j + 3, 32));
      uint2 r0 = tp[(size_t)s0 * 32];
      uint2 r1 = tp[(size_t)s1 * 32];
      uint2 r2 = tp[(size_t)s2 * 32];
      uint2 r3 = tp[(size_t)s3 * 32];
      a.x += w0 * bf_lo(r0.x); a.y += w0 * bf_hi(r0.x); a.z += w0 * bf_lo(r0.y); a.w += w0 * bf_hi(r0.y);
      a.x += w1 * bf_lo(r1.x); a.y += w1 * bf_hi(r1.x); a.z += w1 * bf_lo(r1.y); a.w += w1 * bf_hi(r1.y);
      a.x += w2 * bf_lo(r2.x); a.y += w2 * bf_hi(r2.x); a.z += w2 * bf_lo(r2.y); a.w += w2 * bf_hi(r2.y);
      a.x += w3 * bf_lo(r3.x); a.y += w3 * bf_hi(r3.x); a.z += w3 * bf_lo(r3.y); a.w += w3 * bf_hi(r3.y);
    }
    for (; j < cnt; ++j) {
      int s0 = __shfl(e.x, j, 32);
      float w0 = __int_as_float(__shfl(e.y, j, 32));
      uint2 r0 = tp[(size_t)s0 * 32];
      a.x += w0 * bf_lo(r0.x); a.y += w0 * bf_hi(r0.x); a.z += w0 * bf_lo(r0.y); a.w += w0 * bf_hi(r0.y);
    }
  }
  unsigned int lo = (unsigned int)f2bf(a.x) | ((unsigned int)f2bf(a.y) << 16);
  unsigned int hi = (unsigned int)f2bf(a.z) | ((unsigned int)f2bf(a.w) << 16);
  ((uint2*)(out + (size_t)v * 128))[lane] = make_uint2(lo, hi);
}

// width-64 bf16 aggregation + bias: 16 lanes/node, uint2/lane. fp32 out.
__global__ void k_agg64b(const unsigned short* __restrict__ t, const int2* __restrict__ csr,
                         const int* __restrict__ rp, const float* __restrict__ bias,
                         float* __restrict__ out, int n) {
  int gid = blockIdx.x * blockDim.x + threadIdx.x;
  int v = gid >> 4, lane = gid & 15;
  if (v >= n) return;
  int beg = rp[v], end = rp[v + 1];
  float4 a = make_float4(0.f, 0.f, 0.f, 0.f);
  const uint2* tp = (const uint2*)t + lane;   // row stride = 16 uint2 (64 bf16)
  for (int base = beg; base < end; base += 16) {
    int cnt = end - base; if (cnt > 16) cnt = 16;
    int2 e = csr[base + (lane < cnt ? lane : cnt - 1)];
    int j = 0;
    for (; j + 4 <= cnt; j += 4) {
      int s0 = __shfl(e.x, j + 0, 16), s1 = __shfl(e.x, j + 1, 16);
      int s2 = __shfl(e.x, j + 2, 16), s3 = __shfl(e.x, j + 3, 16);
      float w0 = __int_as_float(__shfl(e.y, j + 0, 16));
      float w1 = __int_as_float(__shfl(e.y, j + 1, 16));
      float w2 = __int_as_float(__shfl(e.y, j + 2, 16));
      float w3 = __int_as_float(__shfl(e.y, j + 3, 16));
      uint2 r0 = tp[(size_t)s0 * 16];
      uint2 r1 = tp[(size_t)s1 * 16];
      uint2 r2 = tp[(size_t)s2 * 16];
      uint2 r3 = tp[(size_t)s3 * 16];
      a.x += w0 * bf_lo(r0.x); a.y += w0 * bf_hi(r0.x); a.z += w0 * bf_lo(r0.y); a.w += w0 * bf_hi(r0.y);
      a.x += w1 * bf_lo(r1.x); a.y += w1 * bf_hi(r1.x); a.z += w1 * bf_lo(r1.y); a.w += w1 * bf_hi(r1.y);
      a.x += w2 * bf_lo(r2.x); a.y += w2 * bf_hi(r2.x); a.z += w2 * bf_lo(r2.y); a.w += w2 * bf_hi(r2.y);
      a.x += w3 * bf_lo(r3.x); a.y += w3 * bf_hi(r3.x); a.z += w3 * bf_lo(r3.y); a.w += w3 * bf_hi(r3.y);
    }
    for (; j < cnt; ++j) {
      int s0 = __shfl(e.x, j, 16);
      float w0 = __int_as_float(__shfl(e.y, j, 16));
      uint2 r0 = tp[(size_t)s0 * 16];
      a.x += w0 * bf_lo(r0.x); a.y += w0 * bf_hi(r0.x); a.z += w0 * bf_lo(r0.y); a.w += w0 * bf_hi(r0.y);
    }
  }
  const float4 b4 = ((const float4*)bias)[lane];
  a.x += b4.x; a.y += b4.y; a.z += b4.z; a.w += b4.w;
  ((float4*)(out + (size_t)v * 64))[lane] = a;
}

// ---------------- GEMMs ----------------

// [n,7] @ [7,128] + b, relu -> bf16 out. block = 2 rows x 128 cols
__global__ __launch_bounds__(256) void k_gemm1(const float* __restrict__ A,
                                               const float* __restrict__ W,
                                               const float* __restrict__ bias,
                                               unsigned short* __restrict__ out, int n) {
  __shared__ float ws[7 * 128];
  for (int j = threadIdx.x; j < 7 * 128; j += 256) ws[j] = W[j];
  __syncthreads();
  int r = blockIdx.x * 2 + (threadIdx.x >> 7);
  int c = threadIdx.x & 127;
  if (r >= n) return;
  const float* a = A + (size_t)r * 7;
  float acc = bias[c];
#pragma unroll
  for (int k = 0; k < 7; ++k) acc += a[k] * ws[k * 128 + c];
  out[(size_t)r * 128 + c] = f2bf(fmaxf(acc, 0.f));
}

// MFMA gemm2: [n,128]bf16 @ W2 + b2, relu -> [n,128]bf16.
// Bt = W2 transposed [col][k] bf16. Wave = 16 rows; 8 col-tiles x 4 K-steps.
// 16x16x32 layout: A-frag lane: m=lane&15, k=(lane>>4)*8+j (contiguous 16B);
// B-frag lane: ncol=lane&15, same k slice (via Bt row-major);
// C/D: col=lane&15, row=(lane>>4)*4+reg  [m89-verified].
__global__ __launch_bounds__(256) void k_gemm2(const unsigned short* __restrict__ A,
                                               const unsigned short* __restrict__ Bt,
                                               const float* __restrict__ bias,
                                               unsigned short* __restrict__ out, int n) {
  int wave = threadIdx.x >> 6, lane = threadIdx.x & 63;
  int am = lane & 15, kg = lane >> 4;
  int r0 = blockIdx.x * 64 + wave * 16;
  int arow = min(r0 + am, n - 1);
  const unsigned short* ap = A + (size_t)arow * 128 + kg * 8;
  f32x4 acc[8] = {};
#pragma unroll
  for (int kb = 0; kb < 4; ++kb) {
    s16x8 a = *(const s16x8*)(ap + kb * 32);
#pragma unroll
    for (int c = 0; c < 8; ++c) {
      s16x8 b = *(const s16x8*)(Bt + (size_t)(c * 16 + am) * 128 + kb * 32 + kg * 8);
      acc[c] = __builtin_amdgcn_mfma_f32_16x16x32_bf16(a, b, acc[c], 0, 0, 0);
    }
  }
#pragma unroll
  for (int c = 0; c < 8; ++c) {
    float bb = bias[c * 16 + am];
#pragma unroll
    for (int j = 0; j < 4; ++j) {
      int r = r0 + kg * 4 + j;
      if (r < n) out[(size_t)r * 128 + c * 16 + am] = f2bf(fmaxf(acc[c][j] + bb, 0.f));
    }
  }
}

// MFMA gemm3: [n,128]bf16 @ W3 -> [n,64]bf16 (no bias/relu).
__global__ __launch_bounds__(256) void k_gemm3(const unsigned short* __restrict__ A,
                                               const unsigned short* __restrict__ Bt,
                                               unsigned short* __restrict__ out, int n) {
  int wave = threadIdx.x >> 6, lane = threadIdx.x & 63;
  int am = lane & 15, kg = lane >> 4;
  int r0 = blockIdx.x * 64 + wave * 16;
  int arow = min(r0 + am, n - 1);
  const unsigned short* ap = A + (size_t)arow * 128 + kg * 8;
  f32x4 acc[4] = {};
#pragma unroll
  for (int kb = 0; kb < 4; ++kb) {
    s16x8 a = *(const s16x8*)(ap + kb * 32);
#pragma unroll
    for (int c = 0; c < 4; ++c) {
      s16x8 b = *(const s16x8*)(Bt + (size_t)(c * 16 + am) * 128 + kb * 32 + kg * 8);
      acc[c] = __builtin_amdgcn_mfma_f32_16x16x32_bf16(a, b, acc[c], 0, 0, 0);
    }
  }
#pragma unroll
  for (int c = 0; c < 4; ++c) {
#pragma unroll
    for (int j = 0; j < 4; ++j) {
      int r = r0 + kg * 4 + j;
      if (r < n) out[(size_t)r * 64 + c * 16 + am] = f2bf(acc[c][j]);
    }
  }
}

// ---------------- mean pool over sorted batch (node-parallel) ----------------

__global__ void k_zero(float* __restrict__ p, int n) {
  int i = blockIdx.x * blockDim.x + threadIdx.x;
  if (i < n) p[i] = 0.f;
}

__global__ void k_pool1(const float* __restrict__ h, const int* __restrict__ batch,
                        float* __restrict__ sums, int n) {
  int gid = blockIdx.x * blockDim.x + threadIdx.x;
  int w = gid >> 6, f = gid & 63;
  int i0 = w * 16;
  if (i0 >= n) return;
  int i1 = min(i0 + 16, n);
  int cur = batch[i0];
  float acc = 0.f;
  for (int i = i0; i < i1; ++i) {
    int g = batch[i];
    if (g != cur) {
      atomicAdd(&sums[cur * 64 + f], acc);
      acc = 0.f; cur = g;
    }
    acc += h[(size_t)i * 64 + f];
  }
  atomicAdd(&sums[cur * 64 + f], acc);
}

__global__ void k_pool2(const float* __restrict__ sums, const int* __restrict__ batch,
                        float* __restrict__ pooled, int n) {
  int g = blockIdx.x, f = threadIdx.x;
  int lo = 0, hi = n;
  while (lo < hi) { int m = (lo + hi) >> 1; if (batch[m] < g) lo = m + 1; else hi = m; }
  int start = lo;
  hi = n;
  while (lo < hi) { int m = (lo + hi) >> 1; if (batch[m] < g + 1) lo = m + 1; else hi = m; }
  float cnt = (float)(lo - start);
  pooled[g * 64 + f] = sums[g * 64 + f] / fmaxf(cnt, 1.f);
}

// ---------------- launch ----------------

extern "C" void kernel_launch(void* const* d_in, const int* in_sizes, int n_in,
                              void* d_out, int out_size, void* d_ws, size_t ws_size,
                              hipStream_t stream) {
  const float* x   = (const float*)d_in[0];
  const int* eidx  = (const int*)d_in[1];
  const int* batch = (const int*)d_in[2];
  const float* W1  = (const float*)d_in[3];
  const float* b1  = (const float*)d_in[4];
  const float* W2  = (const float*)d_in[5];
  const float* b2  = (const float*)d_in[6];
  const float* W3  = (const float*)d_in[7];
  const float* b3  = (const float*)d_in[8];
  float* out = (float*)d_out;

  const int n = in_sizes[0] / 7;       // 50000
  const int e = in_sizes[1] / 2;       // 800000
  const int G = out_size / 64 - n;     // 50
  const int m = e + n;                 // CSR entries incl self-loops

  // workspace carve-up (4B elements)
  float* wsf = (float*)d_ws;
  int*   wsi = (int*)d_ws;
  size_t off = 0;
  int*   deg    = wsi + off; off += n;
  float* dinv   = wsf + off; off += n;
  int*   rp     = wsi + off; off += (size_t)((n + 1 + 3) & ~3);
  int*   cursor = wsi + off; off += n;
  int*   psum   = wsi + off; off += 256;
  float* sums   = wsf + off; off += (size_t)G * 64;
  unsigned short* wb2t = (unsigned short*)(wsf + off); off += 128 * 128 / 2;  // bf16 W2^T
  unsigned short* wb3t = (unsigned short*)(wsf + off); off += 128 * 64 / 2;   // bf16 W3^T
  int2*  csr    = (int2*)(wsi + off); off += (size_t)2 * m;
  float* bufA   = wsf + off; off += (size_t)n * 128;
  float* bufB   = wsf + off; off += (size_t)n * 128;

  // bf16 tensors alias fp32 buffers (dataflow strictly serialized):
  //   t2  (gemm1 out, [n,128])   -> bufB;  consumed by agg128
  //   a2  (agg128 out, [n,128])  -> bufA;  consumed by gemm2
  //   h2  (gemm2 out, [n,128])   -> bufB;  consumed by gemm3 (t2 dead)
  //   t3  (gemm3 out, [n,64])    -> bufA;  consumed by agg64b (a2 dead)
  unsigned short* t2 = (unsigned short*)bufB;
  unsigned short* a2 = (unsigned short*)bufA;
  unsigned short* h2 = (unsigned short*)bufB;
  unsigned short* t3 = (unsigned short*)bufA;

  const int* src = eidx;       // edge_index[0]
  const int* dst = eidx + e;   // edge_index[1]

  const int nb = (n + 255) / 256;

  // CSR build
  k_init_deg<<<nb, 256, 0, stream>>>(deg, n);
  k_count<<<(e + 255) / 256, 256, 0, stream>>>(dst, deg, e);
  k_dinv<<<nb, 256, 0, stream>>>(deg, dinv, n);
  k_scan1<<<nb, 256, 0, stream>>>(deg, rp, psum, n);
  k_scan2<<<1, 256, 0, stream>>>(psum, nb);
  k_scan3<<<nb, 256, 0, stream>>>(rp, cursor, psum, n, m);
  k_scatter<<<(m + 255) / 256, 256, 0, stream>>>(src, dst, dinv, cursor, csr, e, n);
  // zero pooled sums + transpose/convert weights to bf16
  k_zero<<<(G * 64 + 255) / 256, 256, 0, stream>>>(sums, G * 64);
  k_wtr<<<(128 * 128 + 255) / 256, 256, 0, stream>>>(W2, wb2t, 128, 128);
  k_wtr<<<(128 * 64 + 255) / 256, 256, 0, stream>>>(W3, wb3t, 128, 64);

  // layer 1: AGG(x) [n,7] then @W1 + b1, relu -> bf16 t2
  k_agg7<<<((size_t)n * 64 + 255) / 256, 256, 0, stream>>>(x, csr, rp, bufA, n);
  k_gemm1<<<(n + 1) / 2, 256, 0, stream>>>(bufA, W1, b1, t2, n);

  // layer 2: AGG(t2) -> a2 bf16, then MFMA @W2 + b2, relu -> h2 bf16
  k_agg128<<<((size_t)n * 32 + 255) / 256, 256, 0, stream>>>(t2, csr, rp, a2, n);
  k_gemm2<<<(n + 63) / 64, 256, 0, stream>>>(a2, wb2t, b2, h2, n);

  // layer 3: MFMA h2 @ W3 -> t3 bf16, then AGG + b3 -> d_out
  k_gemm3<<<(n + 63) / 64, 256, 0, stream>>>(h2, wb3t, t3, n);
  k_agg64b<<<((size_t)n * 16 + 255) / 256, 256, 0, stream>>>(t3, csr, rp, b3, out, n);

  // mean pool -> d_out tail (node-parallel + finalize)
  const int waves = (n + 15) / 16;
  k_pool1<<<(waves * 64 + 255) / 256, 256, 0, stream>>>(out, batch, sums, n);
  k_pool2<<<G, 64, 0, stream>>>(sums, batch, out + (size_t)n * 64, n);
}